// Round 1
// baseline (148.103 us; speedup 1.0000x reference)
//
#include <hip/hip_runtime.h>
#include <math.h>

#define B_    2
#define C_    64
#define N_    20000
#define K_    16
#define COUT_ 64
#define TN    64                          // nodes per block
#define NBLK  ((N_ + TN - 1) / TN)        // 313 tiles per batch

// ---------------------------------------------------------------------------
// Stage 1: per-node linear transforms.
//   z[b][n][o] = sum_c (W[o][c] - W[o][64+c]) * x[b][c][n] + bias[o]
//   y[b][n][o] = sum_c  W[o][64+c]            * x[b][c][n]
// Layout of z/y: [b][n][o] (node-major) so stage-2 gathers read 256 B
// contiguous per index, coalesced across lanes (lane = o).
// ---------------------------------------------------------------------------
__global__ __launch_bounds__(256, 2)
void stage1_node_transform(const float* __restrict__ x,
                           const float* __restrict__ W,
                           const float* __restrict__ bias,
                           float* __restrict__ zbuf,
                           float* __restrict__ ybuf) {
    // transposed x tile: xt[node][c], row stride 68 floats (17 float4s) so
    // ds_read_b128 rows are 16B-aligned; compute reads are wave-uniform
    // (broadcast) so no read conflicts.
    __shared__ float xt[TN][68];

    const int bi   = blockIdx.x;
    const int b    = bi / NBLK;
    const int n0   = (bi % NBLK) * TN;
    const int t    = threadIdx.x;
    const int lane = t & 63;      // = output channel o
    const int w    = t >> 6;      // wave id 0..3

    // ---- stage x tile into LDS (transposed) ----
    const float* xb = x + (size_t)b * C_ * N_;
    #pragma unroll 1
    for (int r = 0; r < 16; ++r) {
        int flat = r * 256 + t;
        int c  = flat >> 6;
        int nl = flat & 63;
        int n  = n0 + nl;
        float v = (n < N_) ? xb[c * N_ + n] : 0.0f;
        xt[nl][c] = v;
    }

    // ---- load this lane's weight rows into registers (lane = o) ----
    float wz[64], wy[64];
    const float* wrow = W + lane * (2 * C_);
    #pragma unroll
    for (int c4 = 0; c4 < 16; ++c4) {
        float4 w1 = *(const float4*)&wrow[c4 * 4];
        float4 w2 = *(const float4*)&wrow[64 + c4 * 4];
        wz[4 * c4 + 0] = w1.x - w2.x;  wy[4 * c4 + 0] = w2.x;
        wz[4 * c4 + 1] = w1.y - w2.y;  wy[4 * c4 + 1] = w2.y;
        wz[4 * c4 + 2] = w1.z - w2.z;  wy[4 * c4 + 2] = w2.z;
        wz[4 * c4 + 3] = w1.w - w2.w;  wy[4 * c4 + 3] = w2.w;
    }
    const float bo = bias[lane];

    __syncthreads();

    // ---- each wave computes 16 nodes ----
    #pragma unroll 1
    for (int j = 0; j < 16; ++j) {
        int nl = w * 16 + j;
        int n  = n0 + nl;
        float z = bo;     // fold bias into z
        float y = 0.0f;
        #pragma unroll
        for (int c4 = 0; c4 < 16; ++c4) {
            float4 xv = *(const float4*)&xt[nl][c4 * 4];   // wave-uniform b128 broadcast
            z = fmaf(wz[4 * c4 + 0], xv.x, z);  y = fmaf(wy[4 * c4 + 0], xv.x, y);
            z = fmaf(wz[4 * c4 + 1], xv.y, z);  y = fmaf(wy[4 * c4 + 1], xv.y, y);
            z = fmaf(wz[4 * c4 + 2], xv.z, z);  y = fmaf(wy[4 * c4 + 2], xv.z, y);
            z = fmaf(wz[4 * c4 + 3], xv.w, z);  y = fmaf(wy[4 * c4 + 3], xv.w, y);
        }
        if (n < N_) {
            size_t base = ((size_t)b * N_ + n) * 64 + lane;  // coalesced 256B store
            zbuf[base] = z;
            ybuf[base] = y;
        }
    }
}

// ---------------------------------------------------------------------------
// Stage 2: per-edge combine + suppression + max over K.
//   out[b][o][n] = max_k relu(z[i1(k)][o] + y[i0(k)][o]) * 2*sigmoid(-dis_k)
// lane = o; indices + suppression computed in lanes (k = lane&15), broadcast
// via __shfl. Results staged through padded LDS so output stores are
// coalesced along n.
// ---------------------------------------------------------------------------
__global__ __launch_bounds__(256, 2)
void stage2_edge_max(const int* __restrict__ ei,
                     const float* __restrict__ pos,
                     const float* __restrict__ zbuf,
                     const float* __restrict__ ybuf,
                     float* __restrict__ out) {
    __shared__ float tile[TN][65];   // [n_local][o], stride 65 → conflict-free transpose

    const int bi   = blockIdx.x;
    const int b    = bi / NBLK;
    const int n0   = (bi % NBLK) * TN;
    const int t    = threadIdx.x;
    const int lane = t & 63;         // = output channel o
    const int w    = t >> 6;
    const int kk   = lane & 15;      // which edge this lane pre-computes

    const int*   e0 = ei + (size_t)b * N_ * K_;               // edge_index[0][b]
    const int*   e1 = ei + ((size_t)B_ + b) * N_ * K_;        // edge_index[1][b]
    const float* pb = pos + (size_t)b * 3 * N_;
    const float* zb = zbuf + (size_t)b * N_ * 64;
    const float* yb = ybuf + (size_t)b * N_ * 64;

    #pragma unroll 1
    for (int j = 0; j < 16; ++j) {
        int nl = w * 16 + j;
        int n  = n0 + nl;            // wave-uniform
        float m = 0.0f;              // relu(..)*s >= 0, so 0 is a valid identity
        if (n < N_) {
            // lanes 0..15 own edges 0..15 (16..63 are redundant copies)
            int i0 = e0[n * K_ + kk];
            int i1 = e1[n * K_ + kk];
            float dx = pb[i0]          - pb[i1];
            float dy = pb[N_ + i0]     - pb[N_ + i1];
            float dz = pb[2 * N_ + i0] - pb[2 * N_ + i1];
            float dis = sqrtf(dx * dx + dy * dy + dz * dz);
            float s = 2.0f / (1.0f + __expf(dis));   // 2*sigmoid(-dis)

            #pragma unroll
            for (int k = 0; k < 16; ++k) {
                int   i1k = __shfl(i1, k);
                int   i0k = __shfl(i0, k);
                float sk  = __shfl(s, k);
                float zv = zb[(size_t)i1k * 64 + lane];  // coalesced 256B gather
                float yv = yb[(size_t)i0k * 64 + lane];
                float v  = fmaxf(zv + yv, 0.0f) * sk;
                m = fmaxf(m, v);
            }
        }
        tile[nl][lane] = m;
    }

    __syncthreads();

    // transpose out of LDS: coalesced stores along n
    #pragma unroll 1
    for (int r = 0; r < 16; ++r) {
        int flat = r * 256 + t;
        int o  = flat >> 6;
        int nn = flat & 63;
        int n  = n0 + nn;
        if (n < N_) out[((size_t)b * COUT_ + o) * N_ + n] = tile[nn][o];
    }
}

// ---------------------------------------------------------------------------
extern "C" void kernel_launch(void* const* d_in, const int* in_sizes, int n_in,
                              void* d_out, int out_size, void* d_ws, size_t ws_size,
                              hipStream_t stream) {
    const float* x    = (const float*)d_in[0];   // [B, C, N, 1]
    const int*   ei   = (const int*)  d_in[1];   // [2, B, N, K]
    const float* pos  = (const float*)d_in[2];   // [B, 3, N, 1]
    const float* W    = (const float*)d_in[3];   // [COUT, 2C]
    const float* bias = (const float*)d_in[4];   // [COUT]
    float*       out  = (float*)d_out;           // [B, COUT, N, 1]

    float* zbuf = (float*)d_ws;                          // B*N*64 floats
    float* ybuf = zbuf + (size_t)B_ * N_ * 64;           // B*N*64 floats (total ~20.5 MB)

    dim3 grid(B_ * NBLK);   // 626 blocks
    dim3 block(256);
    hipLaunchKernelGGL(stage1_node_transform, grid, block, 0, stream,
                       x, W, bias, zbuf, ybuf);
    hipLaunchKernelGGL(stage2_edge_max, grid, block, 0, stream,
                       ei, pos, zbuf, ybuf, out);
}